// Round 8
// baseline (189.744 us; speedup 1.0000x reference)
//
#include <hip/hip_runtime.h>

#define NB   2048
#define SEQ  200
#define DIM  64
#define NH1  64
#define NH2  16
#define EPSF 1e-9f
#define LOG2E 1.442695040888963f

typedef float    fvec4 __attribute__((ext_vector_type(4)));
typedef short    svec8 __attribute__((ext_vector_type(8)));   // 8 bf16 = 4 VGPRs
typedef unsigned uvec4 __attribute__((ext_vector_type(4)));

// workspace layout (bytes)
#define WS_FRAG_OFF 0                       // 16 MB : Wc frags [b][frag:8][slot:64][8] bf16
#define WS_QT_OFF   (NB * 8192)             // 512 KB : qterm[b][64] f32
#define WS_W2F_OFF  (WS_QT_OFF + NB * 256)  // 2 KB  : W2 frags [kk:2][slot:64][8] bf16
#define WS_BYTES    (WS_W2F_OFF + 2048)

__device__ __forceinline__ short f2bf(float f) {
    unsigned u = __float_as_uint(f);
    u += 0x7fffu + ((u >> 16) & 1u);      // round-to-nearest-even
    return (short)(u >> 16);
}

// packed f32x2 -> bf16x2 (RNE), 1 instruction
__device__ __forceinline__ unsigned pkbf(float lo, float hi) {
    unsigned r;
    asm("v_cvt_pk_bf16_f32 %0, %1, %2" : "=v"(r) : "v"(lo), "v"(hi));
    return r;
}
// raw v_exp_f32: D = 2^S0
__device__ __forceinline__ float exp2fast(float x) {
    float r;
    asm("v_exp_f32 %0, %1" : "=v"(r) : "v"(x));
    return r;
}

// ---------------- prep: block b (< NB) builds batch b's Wc frags + qterm;
//                  block NB builds the W2 frags.  All L2-hot, tiny.
__global__ __launch_bounds__(256)
void din_prep_kernel(const float* __restrict__ q,
                     const float* __restrict__ W1,
                     const float* __restrict__ W2,
                     char* __restrict__ ws)
{
    const int t   = threadIdx.x;
    const int bid = blockIdx.x;
    if (bid < NB) {
        const float* qb = q + (size_t)bid * DIM;
        // 2 (frag,slot) pairs per thread; element j of pair (frag,slot):
        //   d = kk*32+qq*8+j, h = c*16+mm  (frag=(c<<1)|kk, slot=qq*16+mm)
        //   Wc[d][h] = (W1b-W1c)[d][h] + q[d]*W1d[d][h]   (same math as r2)
        #pragma unroll
        for (int pp = 0; pp < 2; ++pp) {
            const int pair = pp * 256 + t;     // 0..511
            const int frag = pair >> 6;
            const int sl   = pair & 63;
            const int c  = frag >> 1;
            const int kk = frag & 1;
            const int qq = sl >> 4;
            const int mm = sl & 15;
            const int h  = c * 16 + mm;
            svec8 v;
            #pragma unroll
            for (int j = 0; j < 8; ++j) {
                const int d = kk * 32 + qq * 8 + j;
                const float wbc  = W1[(64 + d) * NH1 + h] - W1[(128 + d) * NH1 + h];
                const float w1dd = W1[(192 + d) * NH1 + h];
                v[j] = f2bf(fmaf(qb[d], w1dd, wbc));
            }
            *(svec8*)(ws + WS_FRAG_OFF + (size_t)bid * 8192 + pair * 16) = v;
        }
        // qterm[h] = sum_d q[d] * (W1a + W1c)[d][h]
        if (t < 64) {
            const int h = t;
            float acc = 0.f;
            #pragma unroll 8
            for (int d = 0; d < 64; ++d)
                acc = fmaf(qb[d], W1[d * NH1 + h] + W1[(128 + d) * NH1 + h], acc);
            ((float*)(ws + WS_QT_OFF))[(size_t)bid * 64 + h] = acc;
        }
    } else {
        // W2 frags (A operand of transposed phase-2): elem j of (kk,slot):
        //   A[row=j2=mm][k=kk*32+qq*8+j] = W2[kk*32+qq*8+j][mm]
        if (t < 128) {
            const int kk = t >> 6;
            const int sl = t & 63;
            const int qq = sl >> 4;
            const int mm = sl & 15;
            svec8 f;
            #pragma unroll
            for (int j = 0; j < 8; ++j) {
                const int h = kk * 32 + qq * 8 + j;
                f[j] = f2bf(W2[h * NH2 + mm]);
            }
            *(svec8*)(ws + WS_W2F_OFF + t * 16) = f;
        }
    }
}

// ---------------- main (workspace path): no W1 reads, no setup barriers.
// LDS: h1f 8 KB + outp 1 KB.
#define H1F_OFF    0
#define OUTP_OFF   8192
#define SMEM_BYTES 9216

__global__ __launch_bounds__(256, 3)
void din_attn_ws(const float* __restrict__ key,      // [B,200,64]
                 const int*   __restrict__ seqlen,   // [B,1]
                 const char*  __restrict__ ws,
                 const float* __restrict__ alpha1v,
                 const float* __restrict__ mean1v,
                 const float* __restrict__ var1v,
                 const float* __restrict__ alpha2v,
                 const float* __restrict__ mean2v,
                 const float* __restrict__ var2v,
                 const float* __restrict__ W3,       // [16]
                 float* __restrict__ out)            // [B,64]
{
    __shared__ __align__(16) char smem[SMEM_BYTES];
    char*  h1f  = smem + H1F_OFF;
    float* outp = (float*)(smem + OUTP_OFF);

    const int b    = blockIdx.x;
    const int t    = threadIdx.x;
    const int lane = t & 63;
    const int wave = __builtin_amdgcn_readfirstlane(t >> 6);
    const int qd4  = lane >> 4;     // quad 0..3
    const int m    = lane & 15;

    const float* kb = key + (size_t)b * (SEQ * DIM);
    int nseq = seqlen[b];
    nseq = nseq < SEQ ? nseq : SEQ;

    // first k-tile loads issued immediately (hide under frag/param loads)
    int rm0 = wave * 16 + m;
    rm0 = rm0 < SEQ ? rm0 : SEQ - 1;
    const float* arow0 = kb + rm0 * DIM + (qd4 << 3);
    fvec4 f0 = *(const fvec4*)(arow0);
    fvec4 f1 = *(const fvec4*)(arow0 + 4);
    fvec4 f2 = *(const fvec4*)(arow0 + 32);
    fvec4 f3 = *(const fvec4*)(arow0 + 36);

    // Wc frags straight from workspace (8 coalesced dwordx4)
    const char* fb = ws + WS_FRAG_OFF + (size_t)b * 8192 + (lane << 4);
    svec8 wcf[4][2];
    #pragma unroll
    for (int c = 0; c < 4; ++c)
        #pragma unroll
        for (int kk = 0; kk < 2; ++kk)
            wcf[c][kk] = *(const svec8*)(fb + (((c << 1) | kk) << 10));

    // W2 frags from workspace
    svec8 w2f[2];
    #pragma unroll
    for (int kk = 0; kk < 2; ++kk)
        w2f[kk] = *(const svec8*)(ws + WS_W2F_OFF + ((kk << 6) + lane) * 16);

    // per-batch bias qterm[b][c*16+m]
    const float* qtg = (const float*)(ws + WS_QT_OFF) + (size_t)b * 64;
    float qtermv[4];
    #pragma unroll
    for (int c = 0; c < 4; ++c) qtermv[c] = qtg[c * 16 + m];

    // dice1 params for h = c*16 + m; r1p pre-scaled by log2(e) (raw v_exp)
    float a1p[4], o1p[4], m1p[4], r1p[4];
    #pragma unroll
    for (int c = 0; c < 4; ++c) {
        a1p[c] = alpha1v[c * 16 + m];
        o1p[c] = 1.f - a1p[c];
        m1p[c] = mean1v[c * 16 + m];
        r1p[c] = rsqrtf(var1v[c * 16 + m] + EPSF) * LOG2E;
    }
    // dice2 params for j = qd4*4 + reg
    float a2p[4], o2p[4], m2p[4], r2p[4], w3p[4];
    #pragma unroll
    for (int reg = 0; reg < 4; ++reg) {
        const int j = qd4 * 4 + reg;
        a2p[reg] = alpha2v[j];
        o2p[reg] = 1.f - a2p[reg];
        m2p[reg] = mean2v[j];
        r2p[reg] = rsqrtf(var2v[j] + EPSF) * LOG2E;
        w3p[reg] = W3[j];
    }

    char* myh1 = h1f + (wave << 11);   // 2 KB private transpose buffer

    fvec4 oa0 = (fvec4){0.f,0.f,0.f,0.f};   // out cols qd4*8+0..3
    fvec4 oa1 = (fvec4){0.f,0.f,0.f,0.f};   // out cols qd4*8+4..7
    fvec4 oa2 = (fvec4){0.f,0.f,0.f,0.f};   // out cols 32+qd4*8+0..3
    fvec4 oa3 = (fvec4){0.f,0.f,0.f,0.f};   // out cols 32+qd4*8+4..7

    // ---- barrier-free rotated main loop (byte-identical to r7)
    int rb = wave * 16;
    if (rb < nseq) {
        for (;;) {
            const int rbn = rb + 64;
            int rn = rbn + m;
            rn = rn < SEQ ? rn : SEQ - 1;
            const float* brow = kb + rn * DIM + (qd4 << 3);
            const fvec4 g0 = *(const fvec4*)(brow);
            const fvec4 g1 = *(const fvec4*)(brow + 4);
            const fvec4 g2 = *(const fvec4*)(brow + 32);
            const fvec4 g3 = *(const fvec4*)(brow + 36);

            // A-frags via packed bf16 converts (1 inst / 2 floats)
            uvec4 ua0, ua1;
            ua0[0] = pkbf(f0[0], f0[1]);  ua0[1] = pkbf(f0[2], f0[3]);
            ua0[2] = pkbf(f1[0], f1[1]);  ua0[3] = pkbf(f1[2], f1[3]);
            ua1[0] = pkbf(f2[0], f2[1]);  ua1[1] = pkbf(f2[2], f2[3]);
            ua1[2] = pkbf(f3[0], f3[1]);  ua1[3] = pkbf(f3[2], f3[3]);
            const svec8 a0 = __builtin_bit_cast(svec8, ua0);
            const svec8 a1 = __builtin_bit_cast(svec8, ua1);

            // phase 1: x = k @ Wc + qterm
            fvec4 acc[4];
            #pragma unroll
            for (int c = 0; c < 4; ++c) {
                fvec4 a = (fvec4){qtermv[c], qtermv[c], qtermv[c], qtermv[c]};
                a = __builtin_amdgcn_mfma_f32_16x16x32_bf16(a0, wcf[c][0], a, 0, 0, 0);
                a = __builtin_amdgcn_mfma_f32_16x16x32_bf16(a1, wcf[c][1], a, 0, 0, 0);
                acc[c] = a;
            }

            // dice1; h1 -> LDS in frag layout, XOR-swizzled slots
            #pragma unroll
            for (int c = 0; c < 4; ++c) {
                const int kk2 = c >> 1;
                const int qhi = (c & 1) * 2 + (m >> 3);
                #pragma unroll
                for (int reg = 0; reg < 4; ++reg) {
                    const float x  = acc[c][reg];
                    const float tn = (x - m1p[c]) * r1p[c];
                    const float p  = __builtin_amdgcn_rcpf(1.f + exp2fast(-tn));
                    const float h1 = x * fmaf(p, o1p[c], a1p[c]);
                    const int l2  = (qhi << 4) | ((qd4 << 2) | reg);
                    const int l2s = l2 ^ ((l2 >> 3) & 7);
                    *(short*)(myh1 + (kk2 << 10) + (l2s << 4) + ((m & 7) << 1))
                        = f2bf(h1);
                }
            }
            // same-wave write->read; compiler inserts lgkmcnt, no barrier

            // phase 2 (operand-swapped): h2^T = W2^T @ h1^T
            const int slot = lane ^ ((lane >> 3) & 7);
            const svec8 bb0 = *(const svec8*)(myh1 + (slot << 4));
            const svec8 bb1 = *(const svec8*)(myh1 + 1024 + (slot << 4));
            fvec4 acc2 = (fvec4){0.f, 0.f, 0.f, 0.f};
            acc2 = __builtin_amdgcn_mfma_f32_16x16x32_bf16(w2f[0], bb0, acc2, 0, 0, 0);
            acc2 = __builtin_amdgcn_mfma_f32_16x16x32_bf16(w2f[1], bb1, acc2, 0, 0, 0);

            // dice2 + W3
            float s = 0.f;
            #pragma unroll
            for (int reg = 0; reg < 4; ++reg) {
                const float x  = acc2[reg];
                const float tn = (x - m2p[reg]) * r2p[reg];
                const float p  = __builtin_amdgcn_rcpf(1.f + exp2fast(-tn));
                const float hd = x * fmaf(p, o2p[reg], a2p[reg]);
                s = fmaf(hd, w3p[reg], s);
            }
            s += __shfl_xor(s, 16);
            s += __shfl_xor(s, 32);
            const float w = (rb + m < nseq)
                ? __builtin_amdgcn_rcpf(1.f + exp2fast(-s * LOG2E)) : 0.f;

            // phase 3: accumulate w * k-row from registers we hold
            #pragma unroll
            for (int jj = 0; jj < 4; ++jj) {
                oa0[jj] = fmaf(w, f0[jj], oa0[jj]);
                oa1[jj] = fmaf(w, f1[jj], oa1[jj]);
                oa2[jj] = fmaf(w, f2[jj], oa2[jj]);
                oa3[jj] = fmaf(w, f3[jj], oa3[jj]);
            }

            if (rbn >= nseq) break;                    // wave-uniform
            rb = rbn;
            f0 = g0; f1 = g1; f2 = g2; f3 = g3;
        }
    }

    // once-per-kernel reduce over the 16 m-lanes of each q-group
    #pragma unroll
    for (int step = 1; step < 16; step <<= 1) {
        #pragma unroll
        for (int jj = 0; jj < 4; ++jj) {
            oa0[jj] += __shfl_xor(oa0[jj], step);
            oa1[jj] += __shfl_xor(oa1[jj], step);
            oa2[jj] += __shfl_xor(oa2[jj], step);
            oa3[jj] += __shfl_xor(oa3[jj], step);
        }
    }
    if (m == 0) {
        float* op = outp + wave * 64 + (qd4 << 3);
        *(fvec4*)(op)          = oa0;
        *(fvec4*)(op + 4)      = oa1;
        *(fvec4*)(op + 32)     = oa2;
        *(fvec4*)(op + 36)     = oa3;
    }
    __syncthreads();
    if (t < 64) {
        out[(size_t)b * DIM + t] = (outp[t] + outp[64 + t]) +
                                   (outp[128 + t] + outp[192 + t]);
    }
}

// ---------------- fallback (round-7 kernel verbatim): used if ws too small
#define FB_WCB_OFF   0
#define FB_QPART_OFF 8192
#define FB_QALL_OFF  9216
#define FB_SMEM      9472

__global__ __launch_bounds__(256, 3)
void din_attn_fb(const float* __restrict__ q,
                 const float* __restrict__ key,
                 const int*   __restrict__ seqlen,
                 const float* __restrict__ W1,
                 const float* __restrict__ alpha1v,
                 const float* __restrict__ mean1v,
                 const float* __restrict__ var1v,
                 const float* __restrict__ W2,
                 const float* __restrict__ alpha2v,
                 const float* __restrict__ mean2v,
                 const float* __restrict__ var2v,
                 const float* __restrict__ W3,
                 float* __restrict__ out)
{
    __shared__ __align__(16) char smem[FB_SMEM];
    char*  wcb   = smem + FB_WCB_OFF;
    char*  h1f   = smem + FB_WCB_OFF;
    float* qpart = (float*)(smem + FB_QPART_OFF);
    float* qall  = (float*)(smem + FB_QALL_OFF);
    float* outp  = (float*)(smem + FB_QPART_OFF);

    const int b    = blockIdx.x;
    const int t    = threadIdx.x;
    const int lane = t & 63;
    const int wave = __builtin_amdgcn_readfirstlane(t >> 6);
    const int qd4  = lane >> 4;
    const int m    = lane & 15;

    const float* qrow = q + (size_t)b * DIM;
    const float* kb   = key + (size_t)b * (SEQ * DIM);
    int nseq = seqlen[b];
    nseq = nseq < SEQ ? nseq : SEQ;

    int rm0 = wave * 16 + m;
    rm0 = rm0 < SEQ ? rm0 : SEQ - 1;
    const float* arow0 = kb + rm0 * DIM + (qd4 << 3);
    fvec4 f0 = *(const fvec4*)(arow0);
    fvec4 f1 = *(const fvec4*)(arow0 + 4);
    fvec4 f2 = *(const fvec4*)(arow0 + 32);
    fvec4 f3 = *(const fvec4*)(arow0 + 36);

    {
        const int h  = lane;
        const int c  = h >> 4;
        const int mm = h & 15;
        float qt = 0.f;
        #pragma unroll
        for (int i = 0; i < 16; ++i) {
            const int d = wave * 16 + i;
            const float qdv  = qrow[d];
            const float w1a  = W1[(d)       * NH1 + h];
            const float w1b  = W1[(64 + d)  * NH1 + h];
            const float w1c  = W1[(128 + d) * NH1 + h];
            const float w1dd = W1[(192 + d) * NH1 + h];
            const float wc   = (w1b - w1c) + qdv * w1dd;
            qt = fmaf(qdv, w1a + w1c, qt);
            const int frag = (c << 1) | (d >> 5);
            const int ln   = (((d >> 3) & 3) << 4) | mm;
            *(short*)(wcb + (frag << 10) + (ln << 4) + ((d & 7) << 1)) = f2bf(wc);
        }
        qpart[wave * 64 + h] = qt;
    }
    __syncthreads();

    if (t < 64)
        qall[t] = (qpart[t] + qpart[64 + t]) + (qpart[128 + t] + qpart[192 + t]);

    svec8 wcf[4][2];
    #pragma unroll
    for (int c = 0; c < 4; ++c)
        #pragma unroll
        for (int kk = 0; kk < 2; ++kk)
            wcf[c][kk] = *(const svec8*)(wcb + (((c << 1) | kk) << 10) + (lane << 4));

    svec8 w2f[2];
    #pragma unroll
    for (int kk = 0; kk < 2; ++kk) {
        svec8 f;
        #pragma unroll
        for (int j = 0; j < 8; ++j) {
            const int h = kk * 32 + qd4 * 8 + j;
            f[j] = f2bf(W2[h * NH2 + m]);
        }
        w2f[kk] = f;
    }

    float a1p[4], o1p[4], m1p[4], r1p[4];
    #pragma unroll
    for (int c = 0; c < 4; ++c) {
        a1p[c] = alpha1v[c * 16 + m];
        o1p[c] = 1.f - a1p[c];
        m1p[c] = mean1v[c * 16 + m];
        r1p[c] = rsqrtf(var1v[c * 16 + m] + EPSF) * LOG2E;
    }
    float a2p[4], o2p[4], m2p[4], r2p[4], w3p[4];
    #pragma unroll
    for (int reg = 0; reg < 4; ++reg) {
        const int j = qd4 * 4 + reg;
        a2p[reg] = alpha2v[j];
        o2p[reg] = 1.f - a2p[reg];
        m2p[reg] = mean2v[j];
        r2p[reg] = rsqrtf(var2v[j] + EPSF) * LOG2E;
        w3p[reg] = W3[j];
    }

    __syncthreads();

    float qtermv[4];
    #pragma unroll
    for (int c = 0; c < 4; ++c) qtermv[c] = qall[c * 16 + m];

    char* myh1 = h1f + (wave << 11);

    fvec4 oa0 = (fvec4){0.f,0.f,0.f,0.f};
    fvec4 oa1 = (fvec4){0.f,0.f,0.f,0.f};
    fvec4 oa2 = (fvec4){0.f,0.f,0.f,0.f};
    fvec4 oa3 = (fvec4){0.f,0.f,0.f,0.f};

    int rb = wave * 16;
    if (rb < nseq) {
        for (;;) {
            const int rbn = rb + 64;
            int rn = rbn + m;
            rn = rn < SEQ ? rn : SEQ - 1;
            const float* brow = kb + rn * DIM + (qd4 << 3);
            const fvec4 g0 = *(const fvec4*)(brow);
            const fvec4 g1 = *(const fvec4*)(brow + 4);
            const fvec4 g2 = *(const fvec4*)(brow + 32);
            const fvec4 g3 = *(const fvec4*)(brow + 36);

            uvec4 ua0, ua1;
            ua0[0] = pkbf(f0[0], f0[1]);  ua0[1] = pkbf(f0[2], f0[3]);
            ua0[2] = pkbf(f1[0], f1[1]);  ua0[3] = pkbf(f1[2], f1[3]);
            ua1[0] = pkbf(f2[0], f2[1]);  ua1[1] = pkbf(f2[2], f2[3]);
            ua1[2] = pkbf(f3[0], f3[1]);  ua1[3] = pkbf(f3[2], f3[3]);
            const svec8 a0 = __builtin_bit_cast(svec8, ua0);
            const svec8 a1 = __builtin_bit_cast(svec8, ua1);

            fvec4 acc[4];
            #pragma unroll
            for (int c = 0; c < 4; ++c) {
                fvec4 a = (fvec4){qtermv[c], qtermv[c], qtermv[c], qtermv[c]};
                a = __builtin_amdgcn_mfma_f32_16x16x32_bf16(a0, wcf[c][0], a, 0, 0, 0);
                a = __builtin_amdgcn_mfma_f32_16x16x32_bf16(a1, wcf[c][1], a, 0, 0, 0);
                acc[c] = a;
            }

            #pragma unroll
            for (int c = 0; c < 4; ++c) {
                const int kk2 = c >> 1;
                const int qhi = (c & 1) * 2 + (m >> 3);
                #pragma unroll
                for (int reg = 0; reg < 4; ++reg) {
                    const float x  = acc[c][reg];
                    const float tn = (x - m1p[c]) * r1p[c];
                    const float p  = __builtin_amdgcn_rcpf(1.f + exp2fast(-tn));
                    const float h1 = x * fmaf(p, o1p[c], a1p[c]);
                    const int l2  = (qhi << 4) | ((qd4 << 2) | reg);
                    const int l2s = l2 ^ ((l2 >> 3) & 7);
                    *(short*)(myh1 + (kk2 << 10) + (l2s << 4) + ((m & 7) << 1))
                        = f2bf(h1);
                }
            }

            const int slot = lane ^ ((lane >> 3) & 7);
            const svec8 bb0 = *(const svec8*)(myh1 + (slot << 4));
            const svec8 bb1 = *(const svec8*)(myh1 + 1024 + (slot << 4));
            fvec4 acc2 = (fvec4){0.f, 0.f, 0.f, 0.f};
            acc2 = __builtin_amdgcn_mfma_f32_16x16x32_bf16(w2f[0], bb0, acc2, 0, 0, 0);
            acc2 = __builtin_amdgcn_mfma_f32_16x16x32_bf16(w2f[1], bb1, acc2, 0, 0, 0);

            float s = 0.f;
            #pragma unroll
            for (int reg = 0; reg < 4; ++reg) {
                const float x  = acc2[reg];
                const float tn = (x - m2p[reg]) * r2p[reg];
                const float p  = __builtin_amdgcn_rcpf(1.f + exp2fast(-tn));
                const float hd = x * fmaf(p, o2p[reg], a2p[reg]);
                s = fmaf(hd, w3p[reg], s);
            }
            s += __shfl_xor(s, 16);
            s += __shfl_xor(s, 32);
            const float w = (rb + m < nseq)
                ? __builtin_amdgcn_rcpf(1.f + exp2fast(-s * LOG2E)) : 0.f;

            #pragma unroll
            for (int jj = 0; jj < 4; ++jj) {
                oa0[jj] = fmaf(w, f0[jj], oa0[jj]);
                oa1[jj] = fmaf(w, f1[jj], oa1[jj]);
                oa2[jj] = fmaf(w, f2[jj], oa2[jj]);
                oa3[jj] = fmaf(w, f3[jj], oa3[jj]);
            }

            if (rbn >= nseq) break;
            rb = rbn;
            f0 = g0; f1 = g1; f2 = g2; f3 = g3;
        }
    }

    #pragma unroll
    for (int step = 1; step < 16; step <<= 1) {
        #pragma unroll
        for (int jj = 0; jj < 4; ++jj) {
            oa0[jj] += __shfl_xor(oa0[jj], step);
            oa1[jj] += __shfl_xor(oa1[jj], step);
            oa2[jj] += __shfl_xor(oa2[jj], step);
            oa3[jj] += __shfl_xor(oa3[jj], step);
        }
    }
    if (m == 0) {
        float* op = outp + wave * 64 + (qd4 << 3);
        *(fvec4*)(op)          = oa0;
        *(fvec4*)(op + 4)      = oa1;
        *(fvec4*)(op + 32)     = oa2;
        *(fvec4*)(op + 36)     = oa3;
    }
    __syncthreads();
    if (t < 64) {
        out[(size_t)b * DIM + t] = (outp[t] + outp[64 + t]) +
                                   (outp[128 + t] + outp[192 + t]);
    }
}

extern "C" void kernel_launch(void* const* d_in, const int* in_sizes, int n_in,
                              void* d_out, int out_size, void* d_ws, size_t ws_size,
                              hipStream_t stream) {
    const float* q      = (const float*)d_in[0];
    const float* key    = (const float*)d_in[1];
    const int*   seqlen = (const int*)d_in[2];
    const float* W1     = (const float*)d_in[3];
    const float* alpha1 = (const float*)d_in[4];
    const float* mean1  = (const float*)d_in[5];
    const float* var1   = (const float*)d_in[6];
    const float* W2     = (const float*)d_in[7];
    const float* alpha2 = (const float*)d_in[8];
    const float* mean2  = (const float*)d_in[9];
    const float* var2   = (const float*)d_in[10];
    const float* W3     = (const float*)d_in[11];
    float* out          = (float*)d_out;

    if (d_ws != nullptr && ws_size >= (size_t)WS_BYTES) {
        char* ws = (char*)d_ws;
        din_prep_kernel<<<NB + 1, 256, 0, stream>>>(q, W1, W2, ws);
        din_attn_ws<<<NB, 256, 0, stream>>>(key, seqlen, ws,
                                            alpha1, mean1, var1,
                                            alpha2, mean2, var2,
                                            W3, out);
    } else {
        din_attn_fb<<<NB, 256, 0, stream>>>(q, key, seqlen, W1,
                                            alpha1, mean1, var1,
                                            W2, alpha2, mean2, var2,
                                            W3, out);
    }
}